// Round 12
// baseline (199.947 us; speedup 1.0000x reference)
//
#include <hip/hip_runtime.h>
#include <math.h>

#define NN   10000
#define DEG  16
#define SS   128
#define NRBF 20
#define GG   64
#define RC   10.0f
#define PI_F 3.14159265358979323846f
#define NB   8

__device__ __forceinline__ float silu_f(float x){
    return x / (1.0f + __expf(-x));
}

// ---------------------------------------------------------------------------
// Kernel 1: phi (round-8 version, 96 blocks)
// ---------------------------------------------------------------------------
__global__ __launch_bounds__(128) void k_phi(
    const float* __restrict__ emb0,
    const float* __restrict__ w1, const float* __restrict__ b1,
    const float* __restrict__ w2, const float* __restrict__ b2,
    float* __restrict__ phiW){
    __shared__ float s0[SS];
    __shared__ float hL[SS];
    __shared__ float part[2][4];
    int t = threadIdx.x, bid = blockIdx.x;
    s0[t] = 128.0f * emb0[t];
    __syncthreads();
    float acc = 0.0f;
    #pragma unroll 8
    for (int s = 0; s < SS; s++)
        acc = fmaf(s0[s], w1[s*SS + t], acc);
    hL[t] = silu_f(acc + b1[t]);
    __syncthreads();
    int c0 = bid * 4;
    float4 wq = *((const float4*)(w2 + t*3*SS + c0));
    float h = hL[t];
    float p[4] = {h*wq.x, h*wq.y, h*wq.z, h*wq.w};
    int lane = t & 63, wid = t >> 6;
    #pragma unroll
    for (int j = 0; j < 4; j++){
        float v = p[j];
        for (int off = 32; off; off >>= 1) v += __shfl_down(v, off);
        if (lane == 0) part[wid][j] = v;
    }
    __syncthreads();
    if (t < 4) phiW[c0 + t] = b2[c0 + t] + part[0][t] + part[1][t];
}

// ---------------------------------------------------------------------------
// Kernel 2: FUSED edge + update, quad-channel Phase B (R6 mechanism, bugs
// fixed). NB=8 nodes / 128 threads / 1250 blocks.
// Thread = (cq=t&31 -> channels 4cq..4cq+3, pr=t>>5 -> nodes 2pr,2pr+1).
// Weight loads are float4 (coalesced 16B/lane; lanes 0..31 cover the full
// 512B row): 2 loads feed 16 FMAs -> 2x R7's FMA:load ratio, 4x fewer load
// instructions. R6's failures fixed: intermediates stored [node][ch] so each
// thread's result is ONE conflict-free float4 LDS write (R6's [ch][node]
// scalar writes were 32-way conflicts, 1.76M); epilogue exchanges via LDS
// then does stride-1 coalesced atomics (R6's stride-4 atomics 4x'd
// WRITE_SIZE). dL reduce = single width-32 shuffle (node's channels live in
// one 32-lane group). Phase A = R7-proven code at NB=8.
// ---------------------------------------------------------------------------
__global__ __launch_bounds__(128) void k_node(
    const float* __restrict__ evd, const float* __restrict__ elen,
    const float* __restrict__ filt_w, const float* __restrict__ filt_b,
    const float* __restrict__ phiW,
    const float* __restrict__ u_w, const float* __restrict__ v_w,
    const float* __restrict__ upd_w1, const float* __restrict__ upd_b1,
    const float* __restrict__ upd_w2, const float* __restrict__ upd_b2,
    const int* __restrict__ ngi, float* __restrict__ gs){
    __shared__ float rS[NB*DEG];
    __shared__ float mcL[NB*DEG];
    __shared__ float frL[NB*DEG];
    __shared__ float eV[NB*DEG][3];
    __shared__ float rbfL[NB*DEG][NRBF];
    __shared__ float invD[NB];
    __shared__ __align__(16) float svT[NB][SS];     // [node][ch] sv
    __shared__ __align__(16) float xT[NB][2*SS];    // [node][i]: i<SS Vnorm, i>=SS state
    __shared__ __align__(16) float h2T[NB][SS];     // [node][ch] h; reused for epilogue exchange
    __shared__ float dL[NB];
    __shared__ int   gL[NB];
    int t  = threadIdx.x;
    int cq = t & 31;          // channel quad -> channels c0..c0+3
    int c0 = cq * 4;
    int pr = t >> 5;          // node pair -> nodes 2pr, 2pr+1
    int n0 = blockIdx.x * NB;

    // ---------------- Phase A: edge processing (R7-proven, NB=8) ----------
    {
        int e = n0*DEG + t;                 // t < 128 = NB*DEG exactly
        float x = evd[3*e+0], y = evd[3*e+1], z = evd[3*e+2];
        float r = sqrtf(x*x + y*y + z*z);
        float len  = elen[e];
        float mask = (fabsf(len) <= RC) ? 1.0f : 0.0f;
        float cut  = (r < RC) ? 0.5f*(cosf(PI_F*r*(1.0f/RC)) + 1.0f) : 0.0f;
        rS[t]  = fmaxf(r, 1e-12f);
        mcL[t] = mask * cut;
        frL[t] = mask * r * r;
        eV[t][0] = x; eV[t][1] = y; eV[t][2] = z;
    }
    if (t < NB) gL[t] = ngi[n0 + t];
    __syncthreads();
    for (int idx = t; idx < NB*DEG*NRBF; idx += 128){
        int e = idx / NRBF, k = idx % NRBF;
        float rs = rS[e];
        rbfL[e][k] = sinf((float)(k+1) * (PI_F/RC) * rs) / rs;
    }
    if (t < NB){
        float s = 0.0f;
        for (int j = 0; j < DEG; j++) s += frL[t*DEG + j];
        float fbn = sqrtf(s);
        invD[t] = (fbn > 0.0f) ? 1.0f/fbn : 1.0f;
    }
    __syncthreads();

    {
        int gc1 = SS + t;      // m2 channel (-> state)
        int gc2 = 2*SS + t;    // m3 channel (-> sv)
        float fw1[NRBF], fw2[NRBF];
        #pragma unroll
        for (int k = 0; k < NRBF; k++){
            fw1[k] = filt_w[k*(3*SS) + gc1];
            fw2[k] = filt_w[k*(3*SS) + gc2];
        }
        float fb1 = filt_b[gc1], fb2 = filt_b[gc2];
        float ph1 = phiW[gc1],   ph2 = phiW[gc2];
        int   s3  = t % 3;

        for (int b = 0; b < NB; b++){
            float iD = invD[b];
            float acc1 = 0.0f, acc2 = 0.0f;
            for (int e = 0; e < DEG; e++){
                int ee = b*DEG + e;
                float mc = mcL[ee];
                if (mc == 0.0f) continue;   // wave-uniform skip
                const float4* rv = (const float4*)(&rbfL[ee][0]);
                float4 r0 = rv[0], r1 = rv[1], r2 = rv[2], r3 = rv[3], r4 = rv[4];
                float rr[20] = {r0.x,r0.y,r0.z,r0.w, r1.x,r1.y,r1.z,r1.w,
                                r2.x,r2.y,r2.z,r2.w, r3.x,r3.y,r3.z,r3.w,
                                r4.x,r4.y,r4.z,r4.w};
                float w1v = fb1, w2v = fb2;
                #pragma unroll
                for (int k = 0; k < NRBF; k++){
                    w1v = fmaf(rr[k], fw1[k], w1v);
                    w2v = fmaf(rr[k], fw2[k], w2v);
                }
                acc1 = fmaf(ph1*mc, w1v, acc1);
                acc2 = fmaf(ph2*mc*eV[ee][s3]*iD, w2v, acc2);
            }
            svT[b][t]      = acc2;   // sv   (stride-1 lanes: conflict-free)
            xT[b][SS + t]  = acc1;   // state
        }
    }
    __syncthreads();

    // ---------------- Phase B: quad-channel update ----------------
    // ---- loop1: U/V for channels c0..c0+3, nodes 2pr,2pr+1
    float accU[2][4], accV[2][4];
    #pragma unroll
    for (int b = 0; b < 2; b++)
        #pragma unroll
        for (int j = 0; j < 4; j++){ accU[b][j]=0.f; accV[b][j]=0.f; }
    for (int s = 0; s < SS; s++){
        float4 wu = *((const float4*)(u_w + s*SS + c0));
        float4 wv = *((const float4*)(v_w + s*SS + c0));
        float wua[4] = {wu.x,wu.y,wu.z,wu.w};
        float wva[4] = {wv.x,wv.y,wv.z,wv.w};
        float sn[2] = { svT[2*pr+0][s], svT[2*pr+1][s] };   // broadcast reads
        #pragma unroll
        for (int b = 0; b < 2; b++)
            #pragma unroll
            for (int j = 0; j < 4; j++){
                accU[b][j] = fmaf(sn[b], wua[j], accU[b][j]);
                accV[b][j] = fmaf(sn[b], wva[j], accV[b][j]);
            }
    }
    // dL: node's 128 channels live entirely in this 32-lane group
    #pragma unroll
    for (int b = 0; b < 2; b++){
        float p = accU[b][0]*accV[b][0] + accU[b][1]*accV[b][1]
                + accU[b][2]*accV[b][2] + accU[b][3]*accV[b][3];
        #pragma unroll
        for (int off = 16; off; off >>= 1) p += __shfl_down(p, off, 32);
        if (cq == 0) dL[2*pr + b] = p;
    }
    // Vnorm = sqrt(3 v^2): ONE float4 write per node (conflict-free row)
    #pragma unroll
    for (int b = 0; b < 2; b++){
        float4 q;
        q.x = sqrtf(3.f*accV[b][0]*accV[b][0]);
        q.y = sqrtf(3.f*accV[b][1]*accV[b][1]);
        q.z = sqrtf(3.f*accV[b][2]*accV[b][2]);
        q.w = sqrtf(3.f*accV[b][3]*accV[b][3]);
        *((float4*)(&xT[2*pr+b][c0])) = q;
    }
    __syncthreads();

    // ---- loop2: h = silu(x @ upd_w1 + b1), 256 inputs
    float accH[2][4];
    #pragma unroll
    for (int b = 0; b < 2; b++)
        #pragma unroll
        for (int j = 0; j < 4; j++) accH[b][j] = 0.f;
    for (int i = 0; i < 2*SS; i++){
        float4 w = *((const float4*)(upd_w1 + i*SS + c0));
        float wa[4] = {w.x,w.y,w.z,w.w};
        float xv[2] = { xT[2*pr+0][i], xT[2*pr+1][i] };
        #pragma unroll
        for (int b = 0; b < 2; b++)
            #pragma unroll
            for (int j = 0; j < 4; j++)
                accH[b][j] = fmaf(xv[b], wa[j], accH[b][j]);
    }
    {
        float4 b1q = *((const float4*)(upd_b1 + c0));
        float b1a[4] = {b1q.x,b1q.y,b1q.z,b1q.w};
        #pragma unroll
        for (int b = 0; b < 2; b++){
            float4 q;
            q.x = silu_f(accH[b][0] + b1a[0]);
            q.y = silu_f(accH[b][1] + b1a[1]);
            q.z = silu_f(accH[b][2] + b1a[2]);
            q.w = silu_f(accH[b][3] + b1a[3]);
            *((float4*)(&h2T[2*pr+b][c0])) = q;
        }
    }
    __syncthreads();

    // ---- loop3: a_sv, a_ss
    float a1[2][4], a2[2][4];
    #pragma unroll
    for (int b = 0; b < 2; b++)
        #pragma unroll
        for (int j = 0; j < 4; j++){ a1[b][j]=0.f; a2[b][j]=0.f; }
    for (int s = 0; s < SS; s++){
        float4 wa4 = *((const float4*)(upd_w2 + s*3*SS + SS   + c0));
        float4 wb4 = *((const float4*)(upd_w2 + s*3*SS + 2*SS + c0));
        float waa[4] = {wa4.x,wa4.y,wa4.z,wa4.w};
        float wba[4] = {wb4.x,wb4.y,wb4.z,wb4.w};
        float hv[2] = { h2T[2*pr+0][s], h2T[2*pr+1][s] };
        #pragma unroll
        for (int b = 0; b < 2; b++)
            #pragma unroll
            for (int j = 0; j < 4; j++){
                a1[b][j] = fmaf(hv[b], waa[j], a1[b][j]);
                a2[b][j] = fmaf(hv[b], wba[j], a2[b][j]);
            }
    }
    __syncthreads();   // all loop3 reads of h2T done before exchange reuse

    // ---- epilogue: LDS exchange -> stride-1 coalesced atomics
    {
        float4 bsvq = *((const float4*)(upd_b2 + SS   + c0));
        float4 bssq = *((const float4*)(upd_b2 + 2*SS + c0));
        float bsva[4] = {bsvq.x,bsvq.y,bsvq.z,bsvq.w};
        float bssa[4] = {bssq.x,bssq.y,bssq.z,bssq.w};
        #pragma unroll
        for (int b = 0; b < 2; b++){
            float d3 = 3.0f * dL[2*pr + b];
            float4 q;
            q.x = (a2[b][0] + bssa[0]) + d3*(a1[b][0] + bsva[0]);
            q.y = (a2[b][1] + bssa[1]) + d3*(a1[b][1] + bsva[1]);
            q.z = (a2[b][2] + bssa[2]) + d3*(a1[b][2] + bsva[2]);
            q.w = (a2[b][3] + bssa[3]) + d3*(a1[b][3] + bsva[3]);
            *((float4*)(&h2T[2*pr+b][c0])) = q;    // reuse h2T as exchange buf
        }
    }
    __syncthreads();
    #pragma unroll
    for (int n = 0; n < NB; n++){
        atomicAdd(&gs[gL[n]*SS + t], h2T[n][t]);   // lanes stride-1: coalesced
    }
}

// ---------------------------------------------------------------------------
// Kernel 3: readout per graph (unchanged)
// ---------------------------------------------------------------------------
__global__ __launch_bounds__(128) void k_out(
    const float* __restrict__ gs,
    const float* __restrict__ w1, const float* __restrict__ b1,
    const float* __restrict__ w2, const float* __restrict__ b2,
    float* __restrict__ out){
    __shared__ float gsL[SS];
    __shared__ float red[2];
    int g = blockIdx.x, t = threadIdx.x;
    gsL[t] = gs[g*SS + t];
    __syncthreads();
    float acc = b1[t];
    #pragma unroll 4
    for (int s = 0; s < SS; s++) acc = fmaf(gsL[s], w1[s*SS + t], acc);
    float p = silu_f(acc) * w2[t];
    for (int off = 32; off; off >>= 1) p += __shfl_down(p, off);
    if ((t & 63) == 0) red[t >> 6] = p;
    __syncthreads();
    if (t == 0) out[g] = red[0] + red[1] + b2[0];
}

extern "C" void kernel_launch(void* const* d_in, const int* in_sizes, int n_in,
                              void* d_out, int out_size, void* d_ws, size_t ws_size,
                              hipStream_t stream) {
    const float* evd     = (const float*)d_in[0];
    const float* elen    = (const float*)d_in[1];
    // d_in[2] = node_from: edges of node n are [16n,16n+16) with from==n
    const int*   ngi     = (const int*)  d_in[3];
    // d_in[4] = num_graphs (device scalar) — G=64 fixed by setup
    const float* emb0    = (const float*)d_in[5];
    const float* phi_w1  = (const float*)d_in[6];
    const float* phi_b1  = (const float*)d_in[7];
    const float* phi_w2  = (const float*)d_in[8];
    const float* phi_b2  = (const float*)d_in[9];
    const float* filt_w  = (const float*)d_in[10];
    const float* filt_b  = (const float*)d_in[11];
    const float* u_w     = (const float*)d_in[12];
    const float* v_w     = (const float*)d_in[13];
    const float* upd_w1  = (const float*)d_in[14];
    const float* upd_b1  = (const float*)d_in[15];
    const float* upd_w2  = (const float*)d_in[16];
    const float* upd_b2  = (const float*)d_in[17];
    const float* out_w1  = (const float*)d_in[18];
    const float* out_b1  = (const float*)d_in[19];
    const float* out_w2  = (const float*)d_in[20];
    const float* out_b2  = (const float*)d_in[21];

    float* ws    = (float*)d_ws;
    float* phiW  = ws;                       // 384 (pad to 512)
    float* gs    = ws + 512;                 // G*S

    hipMemsetAsync(gs, 0, GG*SS*sizeof(float), stream);
    k_phi<<<96, 128, 0, stream>>>(emb0, phi_w1, phi_b1, phi_w2, phi_b2, phiW);
    k_node<<<NN/NB, 128, 0, stream>>>(evd, elen, filt_w, filt_b, phiW,
                                      u_w, v_w, upd_w1, upd_b1, upd_w2, upd_b2,
                                      ngi, gs);
    k_out<<<GG, 128, 0, stream>>>(gs, out_w1, out_b1, out_w2, out_b2, (float*)d_out);
}